// Round 1
// 643.329 us; speedup vs baseline: 1.0843x; 1.0843x over previous
//
#include <hip/hip_runtime.h>
#include <math.h>
#include <stdint.h>

// Problem constants (fixed by the reference)
#define NROWS 200000
#define DDIM  512
#define HDIM  256
#define KHEADS 64
#define NB    32                 // rows per tile iteration
#define NITER (NROWS / NB)       // 6250 exactly
#define GRID  512                // 2 blocks/CU

typedef __attribute__((ext_vector_type(8))) short bf16x8;   // MFMA A/B frag (guide §3)
typedef __attribute__((ext_vector_type(4))) float f32x4;    // MFMA C/D frag

__device__ __forceinline__ uint32_t f2bf1(float x) {        // fp32 -> bf16 bits (RNE)
    uint32_t u = __float_as_uint(x);
    return (u + 0x7FFFu + ((u >> 16) & 1u)) >> 16;
}
// pack two fp32 -> 2xbf16 in one VALU op (v_cvt_pk_bf16_f32 is RNE, same as manual path)
__device__ __forceinline__ uint32_t pk2(float a, float b) {
    uint32_t r;
    asm("v_cvt_pk_bf16_f32 %0, %1, %2" : "=v"(r) : "v"(a), "v"(b));
    return r;
}

// ---------------------------------------------------------------------------
// prep: qwkb[k][d] = bf16( (sum_h q[k,h]*Wk[k,h,d]) / 16 )
// grid 512 = (k, d-octant), 256 thr = 64 d-lanes x 4 h-segments
__global__ __launch_bounds__(256)
void prep(const float* __restrict__ q, const float* __restrict__ Wk,
          unsigned short* __restrict__ qwkb)
{
    const int k    = blockIdx.x >> 3;
    const int dq   = blockIdx.x & 7;
    const int t    = threadIdx.x;
    const int cd   = t & 63;
    const int hseg = t >> 6;
    const int d    = dq * 64 + cd;
    const float* wk = Wk + ((size_t)k << 17);
    const float* qk = q + (k << 8);
    const float* wp = wk + (hseg * 64) * 512 + d;
    const float* qp = qk + hseg * 64;
    float s0 = 0.f, s1 = 0.f, s2 = 0.f, s3 = 0.f;
    #pragma unroll 4
    for (int h = 0; h < 64; h += 4) {
        s0 = fmaf(qp[h],     wp[(h    ) * 512], s0);
        s1 = fmaf(qp[h + 1], wp[(h + 1) * 512], s1);
        s2 = fmaf(qp[h + 2], wp[(h + 2) * 512], s2);
        s3 = fmaf(qp[h + 3], wp[(h + 3) * 512], s3);
    }
    float s = (s0 + s1) + (s2 + s3);
    __shared__ float red[4][64];
    red[hseg][cd] = s;
    __syncthreads();
    if (t < 64) {
        float tot = (red[0][t] + red[1][t]) + (red[2][t] + red[3][t]);
        qwkb[(k << 9) + dq * 64 + t] = (unsigned short)f2bf1(tot * 0.0625f);
    }
}

// qbk[k] = (q[k]·bk[k]) / 16  — tiny
__global__ void qbk_kernel(const float* __restrict__ q, const float* __restrict__ bk,
                           float* __restrict__ qbk)
{
    int k = threadIdx.x;
    const float4* q4 = (const float4*)(q + (k << 8));
    const float4* b4 = (const float4*)(bk + (k << 8));
    float s = 0.f;
    for (int i = 0; i < 64; ++i) {
        float4 a = q4[i], b = b4[i];
        s += a.x * b.x + a.y * b.y + a.z * b.z + a.w * b.w;
    }
    qbk[k] = s * 0.0625f;
}

// ---------------------------------------------------------------------------
// fused_attn: per 32-row tile: stage e->bf16 LDS (two frag layouts),
// C1[row,head] = e·qWk^T via MFMA, p=exp(C1+qb), permute C->A layout,
// P[head,dcol] += p·e via MFMA (K=32). Accumulate P in 128 VGPRs.
__global__ __launch_bounds__(256, 2)
void fused_attn(const float* __restrict__ e,
                const unsigned short* __restrict__ qwkb,
                const float* __restrict__ qbk,
                float* __restrict__ pooled, float* __restrict__ lsum,
                float* __restrict__ parts, float* __restrict__ lparts,
                int use_parts)
{
    __shared__ char lds[65536];   // [0,32K): layoutA (GEMM1 A-frags), [32K,64K): layoutB (GEMM2 B-frags)

    const int t    = threadIdx.x;
    const int w    = t >> 6;      // wave 0..3 -> head tile
    const int lane = t & 63;
    const int c    = lane & 15;
    const int Q    = lane >> 4;

    // persistent qWk B-fragments: B[k=quad*8+j][n=head=w*16+c]
    bf16x8 bq[16];
    {
        const char* qb_ = (const char*)qwkb + (w * 16 + c) * 1024 + Q * 16;
        #pragma unroll
        for (int ks = 0; ks < 16; ++ks)
            bq[ks] = *(const bf16x8*)(qb_ + ks * 64);
    }
    const float qbias = qbk[w * 16 + c];

    f32x4 acc[32];
    #pragma unroll
    for (int i = 0; i < 32; ++i) { f32x4 z = {0.f, 0.f, 0.f, 0.f}; acc[i] = z; }
    float l_part = 0.f;

    for (int b = blockIdx.x; b < NITER; b += GRID) {
        __syncthreads();          // previous iteration's LDS reads complete
        // ---- stage 32x512 fp32 -> bf16 LDS, both layouts, 4x4 blocks/thread ----
        const float4* eg = (const float4*)(e + (size_t)b * (NB * DDIM));
        #pragma unroll
        for (int i = 0; i < 4; ++i) {
            const int bb = t + i * 256;
            const int rg = bb >> 7, dg = bb & 127;   // rowgroup(4 rows), dgroup(4 cols)
            float4 v0 = eg[(rg * 4 + 0) * 128 + dg];
            float4 v1 = eg[(rg * 4 + 1) * 128 + dg];
            float4 v2 = eg[(rg * 4 + 2) * 128 + dg];
            float4 v3 = eg[(rg * 4 + 3) * 128 + dg];
            const float* r0 = (const float*)&v0;
            const float* r1 = (const float*)&v1;
            const float* r2 = (const float*)&v2;
            const float* r3 = (const float*)&v3;
            // layoutA: element (row,d): chunk=(row>>4)*16+(d>>5), lane=(row&15)+((d>>3)&3)*16, byte=(d&7)*2
            {
                const int chA  = (rg >> 2) * 16 + (dg >> 3);
                const int lnD  = ((dg >> 1) & 3) * 16;
                const int byA  = (dg & 1) * 8;
                const int base = chA * 1024 + byA;
                const int sw   = chA & 7;
                int ln0 = (((rg & 3) * 4 + 0) + lnD) ^ sw;
                int ln1 = (((rg & 3) * 4 + 1) + lnD) ^ sw;
                int ln2 = (((rg & 3) * 4 + 2) + lnD) ^ sw;
                int ln3 = (((rg & 3) * 4 + 3) + lnD) ^ sw;
                *(uint2*)(lds + base + ln0 * 16) = make_uint2(pk2(r0[0], r0[1]), pk2(r0[2], r0[3]));
                *(uint2*)(lds + base + ln1 * 16) = make_uint2(pk2(r1[0], r1[1]), pk2(r1[2], r1[3]));
                *(uint2*)(lds + base + ln2 * 16) = make_uint2(pk2(r2[0], r2[1]), pk2(r2[2], r2[3]));
                *(uint2*)(lds + base + ln3 * 16) = make_uint2(pk2(r3[0], r3[1]), pk2(r3[2], r3[3]));
            }
            // layoutB: element (row,d): chunk=d>>4, lane=(d&15)+((row>>3)&3)*16, byte=(row&7)*2
            {
                const int chB  = dg >> 2;
                const int lnR  = ((rg >> 1) & 3) * 16;
                const int byB  = (rg & 1) * 8;
                const int base = 32768 + chB * 1024 + byB;
                const int sw   = chB & 7;
                #pragma unroll
                for (int i3 = 0; i3 < 4; ++i3) {
                    int ln = (((dg & 3) * 4 + i3) + lnR) ^ sw;
                    *(uint2*)(lds + base + ln * 16) =
                        make_uint2(pk2(r0[i3], r1[i3]), pk2(r2[i3], r3[i3]));
                }
            }
        }
        __syncthreads();

        // ---- GEMM1: C1'[row,head] for this wave's 16 heads, 2 row-tiles ----
        f32x4 c10 = {0.f, 0.f, 0.f, 0.f};
        f32x4 c11 = {0.f, 0.f, 0.f, 0.f};
        #pragma unroll
        for (int ks = 0; ks < 16; ++ks) {
            const bf16x8 a0 = *(const bf16x8*)(lds + ks * 1024        + ((lane ^ (ks & 7)) * 16));
            const bf16x8 a1 = *(const bf16x8*)(lds + (16 + ks) * 1024 + ((lane ^ ((16 + ks) & 7)) * 16));
            c10 = __builtin_amdgcn_mfma_f32_16x16x32_bf16(a0, bq[ks], c10, 0, 0, 0);
            c11 = __builtin_amdgcn_mfma_f32_16x16x32_bf16(a1, bq[ks], c11, 0, 0, 0);
        }

        // ---- exp (scores ~N(0,0.45): no max-subtraction needed) ----
        float pe0[4], pe1[4];
        #pragma unroll
        for (int r = 0; r < 4; ++r) {
            pe0[r] = __expf(c10[r] + qbias);
            pe1[r] = __expf(c11[r] + qbias);
            l_part += pe0[r] + pe1[r];
        }

        // ---- C-layout -> A-layout permute: A2[head=c][k=row=Q*8+j] ----
        float av[8];
        #pragma unroll
        for (int j = 0; j < 8; ++j) {
            int sq = (2 * Q + (j >> 2)) & 3;
            int sl = c + (sq << 4);
            float v0 = __shfl(pe0[j & 3], sl, 64);
            float v1 = __shfl(pe1[j & 3], sl, 64);
            av[j] = (Q >= 2) ? v1 : v0;
        }
        union { uint32_t u[4]; bf16x8 v; } a2;
        #pragma unroll
        for (int d2 = 0; d2 < 4; ++d2) a2.u[d2] = pk2(av[2 * d2], av[2 * d2 + 1]);

        // ---- GEMM2: P[head,dcol] += A2 · e  (one K=32 MFMA per 16-col tile) ----
        #pragma unroll
        for (int ntd = 0; ntd < 32; ++ntd) {
            const bf16x8 bf_ = *(const bf16x8*)(lds + 32768 + ntd * 1024 + ((lane ^ (ntd & 7)) * 16));
            acc[ntd] = __builtin_amdgcn_mfma_f32_16x16x32_bf16(a2.v, bf_, acc[ntd], 0, 0, 0);
        }
    }

    // ---- merge block partials ----
    float lt = l_part;
    lt += __shfl_xor(lt, 16, 64);
    lt += __shfl_xor(lt, 32, 64);

    if (use_parts) {
        float* pp = parts + (size_t)blockIdx.x * (KHEADS * DDIM);
        #pragma unroll
        for (int ntd = 0; ntd < 32; ++ntd)
            #pragma unroll
            for (int r = 0; r < 4; ++r)
                pp[(w * 16 + Q * 4 + r) * DDIM + ntd * 16 + c] = acc[ntd][r];
        if (Q == 0) lparts[blockIdx.x * KHEADS + w * 16 + c] = lt;
    } else {
        #pragma unroll
        for (int ntd = 0; ntd < 32; ++ntd)
            #pragma unroll
            for (int r = 0; r < 4; ++r)
                atomicAdd(&pooled[(w * 16 + Q * 4 + r) * DDIM + ntd * 16 + c], acc[ntd][r]);
        if (Q == 0) atomicAdd(&lsum[w * 16 + c], lt);
    }
}

// ---------------------------------------------------------------------------
// reduce_parts: pooled[o] = sum_b parts[b][o]; lsum likewise.
// 512 blocks x 256 thr for pooled (each block: 64 outputs = 16 float4,
// 16 b-chunks of 32), + 1 block for lsum. float4 loads, deep unroll:
// ~8KB/wave in flight -> BW-bound (~13 us) instead of latency-bound (~45 us).
__global__ __launch_bounds__(256)
void reduce_parts(const float* __restrict__ parts, const float* __restrict__ lparts,
                  float* __restrict__ pooled, float* __restrict__ lsum)
{
    const int t   = threadIdx.x;
    const int bid = blockIdx.x;
    if (bid < 512) {
        const int o4    = t & 15;                  // float4 slot within block's 16
        const int chunk = t >> 4;                  // 16 chunks x 32 parts-blocks
        const float4* p4 = (const float4*)parts;   // parts row stride = 8192 float4
        const int base4 = bid * 16 + o4;
        float4 s = make_float4(0.f, 0.f, 0.f, 0.f);
        #pragma unroll 8
        for (int b = chunk * 32; b < chunk * 32 + 32; ++b) {
            float4 v = p4[b * 8192 + base4];
            s.x += v.x; s.y += v.y; s.z += v.z; s.w += v.w;
        }
        __shared__ float4 red[16][16];
        red[chunk][o4] = s;
        __syncthreads();
        if (t < 16) {
            float4 a = red[0][t];
            #pragma unroll
            for (int i = 1; i < 16; ++i) {
                float4 v = red[i][t];
                a.x += v.x; a.y += v.y; a.z += v.z; a.w += v.w;
            }
            ((float4*)pooled)[bid * 16 + t] = a;
        }
    } else {
        const int k = t & 63, chunk = t >> 6;      // 4 chunks x 128 parts-blocks
        float s = 0.f;
        #pragma unroll 8
        for (int b = chunk * 128; b < chunk * 128 + 128; ++b)
            s += lparts[b * 64 + k];
        __shared__ float redl[4][64];
        redl[chunk][k] = s;
        __syncthreads();
        if (t < 64) lsum[t] = (redl[0][t] + redl[1][t]) + (redl[2][t] + redl[3][t]);
    }
}

// ---------------------------------------------------------------------------
// finalize_partial: hval = (pooled[k]/l)·Wv[k,h] + bv[k,h];
// atomic partial dots with mu_w / sigma_w. grid 512 = (k, h-group of 32)
__global__ __launch_bounds__(256)
void finalize_partial(const float* __restrict__ pooled, const float* __restrict__ lsum,
                      const float* __restrict__ Wv, const float* __restrict__ bv,
                      const float* __restrict__ mu_w, const float* __restrict__ sigma_w,
                      float* __restrict__ macc, float* __restrict__ sacc)
{
    const int k  = blockIdx.x >> 3;
    const int hg = blockIdx.x & 7;
    const int t  = threadIdx.x;
    __shared__ float pn[DDIM];
    __shared__ float sm[32], ss[32];
    const float inv_l = 1.0f / lsum[k];
    pn[t]       = pooled[(k << 9) + t] * inv_l;
    pn[t + 256] = pooled[(k << 9) + t + 256] * inv_l;
    __syncthreads();
    const int hi = t >> 3, ds = t & 7;
    const int h  = hg * 32 + hi;
    const float4* wv4 = (const float4*)(Wv + ((size_t)(k * 256 + h) << 9));
    const float4* pn4 = (const float4*)pn;
    float s = 0.f;
    #pragma unroll
    for (int i = 0; i < 16; ++i) {
        float4 a  = pn4[ds + i * 8];
        float4 b_ = wv4[ds + i * 8];
        s += a.x * b_.x + a.y * b_.y + a.z * b_.z + a.w * b_.w;
    }
    s += __shfl_down(s, 4, 64);
    s += __shfl_down(s, 2, 64);
    s += __shfl_down(s, 1, 64);
    if (ds == 0) {
        float hval = s + bv[(k << 8) + h];
        sm[hi] = hval * mu_w[h];
        ss[hi] = hval * sigma_w[h];
    }
    __syncthreads();
    if (t == 0) {
        float m = 0.f, sg = 0.f;
        for (int i = 0; i < 32; ++i) { m += sm[i]; sg += ss[i]; }
        atomicAdd(&macc[k], m);
        atomicAdd(&sacc[k], sg);
    }
}

__global__ void final_out(const float* __restrict__ macc, const float* __restrict__ sacc,
                          const float* __restrict__ mu_b, const float* __restrict__ sigma_b,
                          float* __restrict__ out)
{
    int k = threadIdx.x;
    out[k]          = macc[k] + mu_b[0];
    out[KHEADS + k] = __expf(sacc[k] + sigma_b[0]);
}

// ---------------------------------------------------------------------------
extern "C" void kernel_launch(void* const* d_in, const int* in_sizes, int n_in,
                              void* d_out, int out_size, void* d_ws, size_t ws_size,
                              hipStream_t stream)
{
    const float* e       = (const float*)d_in[0];
    const float* q       = (const float*)d_in[1];
    const float* Wk      = (const float*)d_in[2];
    const float* bk      = (const float*)d_in[3];
    const float* Wv      = (const float*)d_in[4];
    const float* bv      = (const float*)d_in[5];
    const float* mu_w    = (const float*)d_in[6];
    const float* mu_b    = (const float*)d_in[7];
    const float* sigma_w = (const float*)d_in[8];
    const float* sigma_b = (const float*)d_in[9];
    float* out = (float*)d_out;

    char* wsb = (char*)d_ws;
    unsigned short* qwkb = (unsigned short*)wsb;        // 65536 B
    float* qbk    = (float*)(wsb + 65536);              // 256 B
    float* pooled = (float*)(wsb + 65792);              // 131072 B
    float* lsum   = (float*)(wsb + 196864);             // 256 B
    float* macc   = (float*)(wsb + 197120);             // 256 B
    float* sacc   = (float*)(wsb + 197376);             // 256 B
    float* parts  = (float*)(wsb + 197632);             // GRID*128KB
    float* lparts = (float*)(wsb + 197632 + (size_t)GRID * KHEADS * DDIM * 4);
    const size_t need = 197632 + (size_t)GRID * KHEADS * DDIM * 4 + (size_t)GRID * KHEADS * 4;
    const int use_parts = (ws_size >= need) ? 1 : 0;

    if (use_parts)
        hipMemsetAsync(macc, 0, 512, stream);                 // macc+sacc
    else
        hipMemsetAsync(pooled, 0, 131072 + 768, stream);      // pooled+lsum+macc+sacc

    prep<<<512, 256, 0, stream>>>(q, Wk, qwkb);
    qbk_kernel<<<1, 64, 0, stream>>>(q, bk, qbk);
    fused_attn<<<GRID, 256, 0, stream>>>(e, qwkb, qbk, pooled, lsum, parts, lparts, use_parts);
    if (use_parts)
        reduce_parts<<<513, 256, 0, stream>>>(parts, lparts, pooled, lsum);
    finalize_partial<<<512, 256, 0, stream>>>(pooled, lsum, Wv, bv, mu_w, sigma_w, macc, sacc);
    final_out<<<1, 64, 0, stream>>>(macc, sacc, mu_b, sigma_b, out);
}